// Round 13
// baseline (200.032 us; speedup 1.0000x reference)
//
#include <hip/hip_runtime.h>
#include <hip/hip_bf16.h>

#define BB 4
#define CC 256
#define CHH 128
#define NN 4096
#define KSHIFT2 17.312340490667562f   // 12 * log2(e); phi pre-scaled by log2(e)
#define LOG2E 1.4426950408889634f

typedef __attribute__((ext_vector_type(8))) short bf16x8;
typedef __attribute__((ext_vector_type(4))) float f32x4;

__device__ __forceinline__ float to_f(float v) { return v; }
__device__ __forceinline__ float to_f(__hip_bfloat16 v) { return __bfloat162float(v); }
__device__ __forceinline__ void st_f(float* p, float v) { *p = v; }
__device__ __forceinline__ void st_f(__hip_bfloat16* p, float v) { *p = __float2bfloat16(v); }
__device__ __forceinline__ unsigned short f2bf(float f) {
    __hip_bfloat16 h = __float2bfloat16(f);
    unsigned short u;
    __builtin_memcpy(&u, &h, 2);
    return u;
}
__device__ __forceinline__ bf16x8 ldb8(const unsigned short* p) { return *(const bf16x8*)p; }

// Raw 2^x: v_exp_f32 IS exp2 in hardware (proven round 23: OCML exp2f cost
// +12pts VALUBusy; this is one instruction).
__device__ __forceinline__ float fexp2(float x) {
    float r;
    asm("v_exp_f32 %0, %1" : "=v"(r) : "v"(x));
    return r;
}

// async global->LDS, 16 B per lane. LDS dest = wave-uniform base + lane*16.
__device__ __forceinline__ void gload_lds16(const unsigned short* g, unsigned short* l) {
    __builtin_amdgcn_global_load_lds(
        (const __attribute__((address_space(1))) unsigned int*)g,
        (__attribute__((address_space(3))) unsigned int*)l, 16, 0, 0);
}

// vectorized 16-element row load (bf16 or f32 wire) -> 16 bf16 u16
__device__ __forceinline__ void load16(const __hip_bfloat16* src, unsigned short* v) {
    bf16x8 a = *(const bf16x8*)src;
    bf16x8 b = *(const bf16x8*)(src + 8);
#pragma unroll
    for (int k = 0; k < 8; ++k) {
        v[k] = ((unsigned short*)&a)[k];
        v[8 + k] = ((unsigned short*)&b)[k];
    }
}
__device__ __forceinline__ void load16(const float* src, unsigned short* v) {
#pragma unroll
    for (int q = 0; q < 4; ++q) {
        f32x4 f = *(const f32x4*)(src + q * 4);
#pragma unroll
        for (int k = 0; k < 4; ++k) v[q * 4 + k] = f2bf(f[k]);
    }
}

// ---------------------------------------------------------------------------
// Inline wire-dtype detection (proven heuristic, rounds 3-10).
// ---------------------------------------------------------------------------
__device__ __forceinline__ int detect_flag_block(const void* tb, int* sflag) {
    int tid = threadIdx.x;
    if (tid < 64) {
        const __hip_bfloat16* p = (const __hip_bfloat16*)tb;
        int big = 0, zero_even = 0;
#pragma unroll
        for (int k = 0; k < 2; ++k) {
            int idx = tid * 2 + k;
            float v = __bfloat162float(p[idx]);
            if (!(fabsf(v) <= 0.5f)) big = 1;
            if ((idx & 1) == 0 && v == 0.0f) zero_even = 1;
        }
        unsigned long long bigm = __ballot(big);
        unsigned long long zm = __ballot(zero_even);
        if (tid == 0) *sflag = (bigm != 0ULL || __popcll(zm) >= 32) ? 1 : 0;
    }
    __syncthreads();
    return *sflag;
}

// ---------------------------------------------------------------------------
// Kernel A: prep only (xtrans deleted round 22). log2(e) folded into phi.
// ---------------------------------------------------------------------------
template <typename T>
__device__ __forceinline__ void prep_body(const T* tw, const T* fw, const T* gw, const T* ow,
                                          const T* tb2, const T* fb, const T* gb, const T* ob,
                                          unsigned short* Wb, unsigned short* OWb,
                                          float* Bf, float* OBf) {
    int idx = blockIdx.x * 256 + threadIdx.x;
    if (idx < 98304) {
        int cv = idx >> 15, rem = idx & 32767;
        const T* src = cv == 0 ? tw : (cv == 1 ? fw : gw);
        float v = to_f(src[rem]);
        if (cv == 1) v *= LOG2E;              // phi scaled: S' = S*log2e
        Wb[idx] = f2bf(v);
    } else if (idx < 131072) {
        OWb[idx - 98304] = f2bf(to_f(ow[idx - 98304]));
    } else if (idx < 131456) {
        int r = idx - 131072;
        int cv = r >> 7, j = r & 127;
        const T* src = cv == 0 ? tb2 : (cv == 1 ? fb : gb);
        float v = to_f(src[j]);
        if (cv == 1) v *= LOG2E;
        Bf[r] = v;
    } else if (idx < 131712) {
        OBf[idx - 131456] = to_f(ob[idx - 131456]);
    }
}

__launch_bounds__(256)
__global__ void prep_kernel(const void* tw, const void* fw, const void* gw, const void* ow,
                            const void* tb2, const void* fb, const void* gb, const void* ob,
                            unsigned short* Wb, unsigned short* OWb, float* Bf, float* OBf) {
    __shared__ int sflag;
    int flag = detect_flag_block(tb2, &sflag);
    if (flag)
        prep_body<float>((const float*)tw, (const float*)fw, (const float*)gw, (const float*)ow,
                         (const float*)tb2, (const float*)fb, (const float*)gb, (const float*)ob,
                         Wb, OWb, Bf, OBf);
    else
        prep_body<__hip_bfloat16>((const __hip_bfloat16*)tw, (const __hip_bfloat16*)fw,
                                  (const __hip_bfloat16*)gw, (const __hip_bfloat16*)ow,
                                  (const __hip_bfloat16*)tb2, (const __hip_bfloat16*)fb,
                                  (const __hip_bfloat16*)gb, (const __hip_bfloat16*)ob,
                                  Wb, OWb, Bf, OBf);
}

// ---------------------------------------------------------------------------
// Kernel B: three 1x1 convs via MFMA, reading x directly with in-kernel
// transpose staging (proven round 22; xt intermediate deleted).
// ---------------------------------------------------------------------------
template <typename T>
__device__ __forceinline__ void conv3_body(const T* __restrict__ x,
                                           const unsigned short* __restrict__ Wb,
                                           const float* __restrict__ Bf,
                                           unsigned short* __restrict__ T1b,
                                           unsigned short* __restrict__ T2t,
                                           unsigned short* __restrict__ T3b,
                                           unsigned short (*t)[272]) {
    int b = blockIdx.y;
    int p0 = blockIdx.x * 16;
    int flat = threadIdx.x;
    int w = flat >> 6, lane = flat & 63, m = lane & 15, quad = lane >> 4;
    {   // stage + transpose: thread c reads 16 consecutive p of row c
        int c = flat;
        const T* src = x + ((size_t)b * CC + c) * NN + p0;
        unsigned short v[16];
        load16(src, v);
#pragma unroll
        for (int pp = 0; pp < 16; ++pp) t[pp][c] = v[pp];   // lanes contiguous in c
    }
    __syncthreads();
    bf16x8 xf[8];
#pragma unroll
    for (int kc = 0; kc < 8; ++kc)
        xf[kc] = ldb8(&t[m][kc * 32 + quad * 8]);
    unsigned short* t1  = T1b + (size_t)b * CHH * NN;
    unsigned short* t2t = T2t + (size_t)b * CHH * NN;   // [p][o], row stride 128
    unsigned short* t3  = T3b + (size_t)b * CHH * NN;   // natural (CH,N)
#pragma unroll
    for (int q = 0; q < 6; ++q) {
        int tt = w * 6 + q;
        int cv = tt >> 3, ot = tt & 7;
        int o0 = ot * 16;
        const unsigned short* wrow = Wb + ((size_t)cv * CHH + o0 + m) * CC;
        f32x4 acc = {0.f, 0.f, 0.f, 0.f};
        __builtin_amdgcn_s_setprio(1);
#pragma unroll
        for (int kc = 0; kc < 8; ++kc) {
            bf16x8 wf = ldb8(&wrow[kc * 32 + quad * 8]);
            acc = __builtin_amdgcn_mfma_f32_16x16x32_bf16(wf, xf[kc], acc, 0, 0, 0);
        }
        __builtin_amdgcn_s_setprio(0);
        unsigned short hv[4];
#pragma unroll
        for (int r = 0; r < 4; ++r)
            hv[r] = f2bf(acc[r] + Bf[cv * CHH + o0 + quad * 4 + r]);
        if (cv == 1) {
            unsigned int lo = (unsigned int)hv[0] | ((unsigned int)hv[1] << 16);
            unsigned int hi = (unsigned int)hv[2] | ((unsigned int)hv[3] << 16);
            int src = (lane & 3) * 16 + (lane >> 2);
            unsigned int tlo = (unsigned int)__shfl((int)lo, src, 64);
            unsigned int thi = (unsigned int)__shfl((int)hi, src, 64);
            unsigned int* dst = (unsigned int*)&t2t[(size_t)(p0 + (lane >> 2)) * CHH +
                                                    o0 + (lane & 3) * 4];
            dst[0] = tlo;
            dst[1] = thi;
        } else {
            unsigned short* outp = (cv == 0) ? t1 : t3;
#pragma unroll
            for (int r = 0; r < 4; ++r)
                outp[(size_t)(o0 + quad * 4 + r) * NN + p0 + m] = hv[r];
        }
    }
}

__launch_bounds__(256)
__global__ void conv3_mfma_kernel(const void* x, const void* tb2,
                                  const unsigned short* __restrict__ Wb,
                                  const float* __restrict__ Bf,
                                  unsigned short* __restrict__ T1b,
                                  unsigned short* __restrict__ T2t,
                                  unsigned short* __restrict__ T3b) {
    __shared__ int sflag;
    __shared__ unsigned short t[16][272];     // 8,704 B transpose tile
    int flag = detect_flag_block(tb2, &sflag);
    if (flag)
        conv3_body<float>((const float*)x, Wb, Bf, T1b, T2t, T3b, t);
    else
        conv3_body<__hip_bfloat16>((const __hip_bfloat16*)x, Wb, Bf, T1b, T2t, T3b, t);
}

// ---------------------------------------------------------------------------
// Kernel C: transpose + stats fused. ROUND 24: stats restructured — audit
// found all 4 waves read IDENTICAL theta (af) fragments (irow has no w
// term) while owning 32 u each. Now each wave owns 64 u (bfr[4][4], +32
// VGPR) and strips halve: 512 stats blocks (strip 0..15 x 256 u, iq 0..7).
// Same MFMA/exp totals, HALF the LDS reads (4 MFMA/read) and half the
// theta staging traffic. Lpart layout unchanged (8 partials).
// Blocks 0..511: stats; blocks 512..1023: X3t transpose.
// ---------------------------------------------------------------------------
__launch_bounds__(256, 4)
__global__ void trans_stats_kernel(const unsigned short* __restrict__ T1b,
                                   const unsigned short* __restrict__ T2t,
                                   const unsigned short* __restrict__ T3b,
                                   unsigned short* __restrict__ X3t,
                                   float* __restrict__ Lpart) {
    __shared__ unsigned short arena[2 * 64 * 128];   // 32 KB
    int flat = threadIdx.x;
    if (blockIdx.x >= 512) {
        // ---- transpose part: X3t (NN x CHH view) <- T3b, 64x64 tiles ----
        int id = blockIdx.x - 512;             // 0..511
        int bz = id >> 7;                      // batch
        int by = (id >> 1) & 63;               // row tile (NN)
        int bx = id & 1;                       // col tile (CHH)
        const unsigned short* in = T3b + (size_t)bz * NN * CHH;
        unsigned short* out = X3t + (size_t)bz * NN * CHH;
        int c0 = bx * 64, r0 = by * 64;
        unsigned short (*t)[68] = (unsigned short (*)[68])arena;
#pragma unroll
        for (int tt = 0; tt < 16; ++tt) {
            int id2 = flat + tt * 256;
            int r = id2 >> 6, c = id2 & 63;
            t[c][r] = in[(size_t)(r0 + r) * CHH + c0 + c];
        }
        __syncthreads();
#pragma unroll
        for (int tt = 0; tt < 16; ++tt) {
            int id2 = flat + tt * 256;
            int c = id2 >> 6, r = id2 & 63;
            out[(size_t)(c0 + c) * NN + r0 + r] = t[c][r];
        }
        return;
    }
    // ---- stats part: colsum exp2(S'-K2), dbuf + single barrier ----
    int blk = blockIdx.x;                    // 0..511
    int b = (blk & 7) >> 1;
    int rest = (blk >> 3) * 2 + (blk & 1);   // 0..127 = strip*8 + iq
    int strip = rest >> 3, iq = rest & 7;    // strip 0..15 (256 u), iq 0..7
    int ibase = iq * 512;
    int w = flat >> 6, lane = flat & 63, m = lane & 15, quad = lane >> 4;
    const unsigned short* A  = T1b + (size_t)b * CHH * NN;
    const unsigned short* Bt = T2t + (size_t)b * CHH * NN;

    int u0w = strip * 256 + w * 64;           // this wave's 64-u window
    bf16x8 bfr[4][4];
#pragma unroll
    for (int g = 0; g < 4; ++g)
#pragma unroll
        for (int kc = 0; kc < 4; ++kc)
            bfr[g][kc] = ldb8(&Bt[(size_t)(u0w + g * 16 + m) * CHH + kc * 32 + quad * 8]);

#define STAGE_TH(dst, ii)                                                          \
    _Pragma("unroll")                                                              \
    for (int i_ = 0; i_ < 4; ++i_) {                                               \
        int sl = i_ * 256 + flat;                                                  \
        int r_ = sl >> 4, ch_ = sl & 15;                                           \
        int c_ = ch_ ^ (r_ & 7);                                                   \
        gload_lds16(&A[(size_t)((ii) + r_) * CHH + c_ * 8],                        \
                    arena + (dst) * 8192 + sl * 8);                                \
    }

    float csum[4] = {0.f, 0.f, 0.f, 0.f};
    STAGE_TH(0, ibase);                      // prologue: tile 0
    __syncthreads();                         // tile 0 ready (vmcnt drained)
    int cur = 0;
    for (int t = 0; t < 8; ++t) {            // 8 i-tiles of 64 in this chunk
        if (t < 7) { STAGE_TH(cur ^ 1, ibase + (t + 1) * 64); }
        const unsigned short* thc = arena + cur * 8192;
#pragma unroll
        for (int s = 0; s < 4; ++s) {
            int irow = s * 16 + m;
            bf16x8 af[4];
#pragma unroll
            for (int kc = 0; kc < 4; ++kc) {
                int ch = (kc * 4 + quad) ^ (irow & 7);
                af[kc] = *(const bf16x8*)&thc[irow * 128 + ch * 8];
            }
            __builtin_amdgcn_s_setprio(1);
#pragma unroll
            for (int g = 0; g < 4; ++g) {
                f32x4 acc = {0.f, 0.f, 0.f, 0.f};
#pragma unroll
                for (int kc = 0; kc < 4; ++kc)
                    acc = __builtin_amdgcn_mfma_f32_16x16x32_bf16(af[kc], bfr[g][kc], acc, 0, 0, 0);
#pragma unroll
                for (int r = 0; r < 4; ++r)
                    csum[g] += fexp2(acc[r] - KSHIFT2);
            }
            __builtin_amdgcn_s_setprio(0);
        }
        if (t < 7) {
            __syncthreads();                 // publishes tile t+1, protects buf t
            cur ^= 1;
        }
    }
#undef STAGE_TH
#pragma unroll
    for (int g = 0; g < 4; ++g) {
        csum[g] += __shfl_xor(csum[g], 16, 64);
        csum[g] += __shfl_xor(csum[g], 32, 64);
        if (lane < 16)
            Lpart[((size_t)iq * BB + b) * NN + u0w + g * 16 + m] = csum[g];
    }
}

// ---------------------------------------------------------------------------
// Kernel D (pass B): Y = P @ X3. Round-23 swapped-S structure (proven
// 47.7 us): raw v_exp_f32 + __log2f; phi pre-scaled by log2e. Unchanged.
// ---------------------------------------------------------------------------
__launch_bounds__(512, 2)
__global__ void attn_mfma_kernel(const unsigned short* __restrict__ T1b,
                                 const unsigned short* __restrict__ T2t,
                                 const unsigned short* __restrict__ X3t,
                                 const float* __restrict__ Lpart,
                                 unsigned short* __restrict__ Yp0,
                                 unsigned short* __restrict__ Yp1,
                                 unsigned short* __restrict__ Yp2,
                                 unsigned short* __restrict__ Yp3) {
    int blk = blockIdx.x;
    int b = (blk & 7) >> 1;
    int rest = (blk >> 3) * 2 + (blk & 1);   // 0..127 = it*4 + uc
    int it = rest >> 2, uc = rest & 3;
    int i0 = it * 128;
    unsigned short* Yp = uc == 0 ? Yp0 : (uc == 1 ? Yp1 : (uc == 2 ? Yp2 : Yp3));
    int flat = threadIdx.x;                   // 0..511
    int w = flat >> 6, lane = flat & 63, m = lane & 15, quad = lane >> 4;
    int ig = w & 3, h = w >> 2;               // i-group (32 rows), j-half/u-half
    const unsigned short* A  = T1b + (size_t)b * CHH * NN;
    const unsigned short* Bt = T2t + (size_t)b * CHH * NN;
    const unsigned short* X3 = X3t + (size_t)b * CHH * NN;

    // LDS arena, 69,632 B:
    //   [     0, 32768) bt   : phi^T tile, swizzled, dbuf 2 x 64x128 bf16
    //   [ 32768, 49152) x3   : X3 tile, swizzled, single 128x64 bf16
    //   [ 49152, 65536) pT   : per-ig P tiles [4][32 rows][64] bf16, XOR-swz
    //   [ 65536, 69632) llh  : 1024 f32 LL values
    __shared__ __align__(16) unsigned char smem[69632];
    unsigned short* bt0 = (unsigned short*)smem;
    unsigned short* x3s = (unsigned short*)(smem + 32768);
    unsigned short* pTg = (unsigned short*)(smem + 49152) + ig * 2048; // [32][64]
    float* llh = (float*)(smem + 65536);

    int ubeg = uc * 1024;
#pragma unroll
    for (int k = 0; k < 2; ++k) {             // LL prologue
        int idx = k * 512 + flat;
        int u = ubeg + idx;
        float s = 0.f;
#pragma unroll
        for (int c = 0; c < 8; ++c)
            s += Lpart[((size_t)c * BB + b) * NN + u];
        llh[idx] = __log2f(s) + KSHIFT2;
    }

    int iw = i0 + ig * 32;                    // this wave's 32 i-rows
    int j0 = h * 64;                          // this wave's 64 j-cols
    bf16x8 ath[2][4];
#pragma unroll
    for (int g = 0; g < 2; ++g)
#pragma unroll
        for (int kc = 0; kc < 4; ++kc)
            ath[g][kc] = ldb8(&A[(size_t)(iw + g * 16 + m) * CHH + kc * 32 + quad * 8]);
    f32x4 yacc[2][4];
#pragma unroll
    for (int g = 0; g < 2; ++g)
#pragma unroll
        for (int js = 0; js < 4; ++js) yacc[g][js] = (f32x4){0.f, 0.f, 0.f, 0.f};

#define STAGE_BT(dst, uu)                                                          \
    _Pragma("unroll")                                                              \
    for (int i_ = 0; i_ < 2; ++i_) {          /* 16 KB */                          \
        int sl = i_ * 512 + flat;                                                  \
        int u_ = sl >> 4, ch_ = sl & 15;                                           \
        int c_ = ch_ ^ (u_ & 7);                                                   \
        gload_lds16(&Bt[(size_t)((uu) + u_) * CHH + c_ * 8],                       \
                    bt0 + (dst) * 8192 + sl * 8);                                  \
    }
#define STAGE_X3(uu)                                                               \
    _Pragma("unroll")                                                              \
    for (int i_ = 0; i_ < 2; ++i_) {          /* 16 KB */                          \
        int sl = i_ * 512 + flat;                                                  \
        int j_ = sl >> 3, ch_ = sl & 7;                                            \
        int c_ = ch_ ^ (j_ & 7);                                                   \
        gload_lds16(&X3[(size_t)j_ * NN + (uu) + c_ * 8], x3s + sl * 8);           \
    }

    STAGE_BT(0, ubeg);                        // prologue: bt tile 0 + x3 tile 0
    STAGE_X3(ubeg);
    __syncthreads();                          // staging drained + llh visible
    int cur = 0;
    for (int t = 0; t < 16; ++t) {
        int u0 = ubeg + t * 64;
        if (t < 15) { STAGE_BT(cur ^ 1, u0 + 64); }   // drains at barrier A
        const unsigned short* btc = bt0 + cur * 8192;
        // ---- S phase (swapped): S^T(32u-half h x 32i), exp, packed P ----
#pragma unroll
        for (int su = 0; su < 2; ++su) {
            int ul = h * 32 + su * 16 + m;    // bt row fed as A-operand rows
            f32x4 a0 = {0.f, 0.f, 0.f, 0.f}, a1 = {0.f, 0.f, 0.f, 0.f};
            __builtin_amdgcn_s_setprio(1);
#pragma unroll
            for (int kc = 0; kc < 4; ++kc) {
                int ch = (kc * 4 + quad) ^ (ul & 7);
                bf16x8 bf = *(const bf16x8*)&btc[ul * 128 + ch * 8];
                a0 = __builtin_amdgcn_mfma_f32_16x16x32_bf16(bf, ath[0][kc], a0, 0, 0, 0);
                a1 = __builtin_amdgcn_mfma_f32_16x16x32_bf16(bf, ath[1][kc], a1, 0, 0, 0);
            }
            __builtin_amdgcn_s_setprio(0);
            // lane holds P^T: i = m (+g*16), u = ubase + r (4 consecutive u)
            int ubase = h * 32 + su * 16 + quad * 4;
            int lb = t * 64 + ubase;
            unsigned int p00 = (unsigned int)f2bf(fexp2(a0[0] - llh[lb + 0])) |
                               ((unsigned int)f2bf(fexp2(a0[1] - llh[lb + 1])) << 16);
            unsigned int p01 = (unsigned int)f2bf(fexp2(a0[2] - llh[lb + 2])) |
                               ((unsigned int)f2bf(fexp2(a0[3] - llh[lb + 3])) << 16);
            unsigned int p10 = (unsigned int)f2bf(fexp2(a1[0] - llh[lb + 0])) |
                               ((unsigned int)f2bf(fexp2(a1[1] - llh[lb + 1])) << 16);
            unsigned int p11 = (unsigned int)f2bf(fexp2(a1[2] - llh[lb + 2])) |
                               ((unsigned int)f2bf(fexp2(a1[3] - llh[lb + 3])) << 16);
            int chs = ((ubase >> 3) ^ (m & 7)) * 8 + (ubase & 7); // swz chunk+off
            unsigned int* d0 = (unsigned int*)&pTg[m * 64 + chs];          // 4B-aligned
            d0[0] = p00; d0[1] = p01;
            unsigned int* d1 = (unsigned int*)&pTg[(16 + m) * 64 + chs];
            d1[0] = p10; d1[1] = p11;
        }
        __syncthreads();                      // A: pT published; x3(t)+bt(t+1) drained
        // ---- PV phase: Y(32i x 64j, cols j0..j0+63) over full 64-u K ----
#pragma unroll
        for (int ku = 0; ku < 2; ++ku) {
            bf16x8 pa0 = *(const bf16x8*)&pTg[m * 64 + ((ku * 4 + quad) ^ (m & 7)) * 8];
            bf16x8 pa1 = *(const bf16x8*)&pTg[(16 + m) * 64 + ((ku * 4 + quad) ^ (m & 7)) * 8];
            __builtin_amdgcn_s_setprio(1);
#pragma unroll
            for (int js = 0; js < 4; ++js) {
                int j = j0 + js * 16 + m;
                int ch = (ku * 4 + quad) ^ (j & 7);
                bf16x8 xb = *(const bf16x8*)&x3s[j * 64 + ch * 8];
                yacc[0][js] = __builtin_amdgcn_mfma_f32_16x16x32_bf16(pa0, xb, yacc[0][js], 0, 0, 0);
                yacc[1][js] = __builtin_amdgcn_mfma_f32_16x16x32_bf16(pa1, xb, yacc[1][js], 0, 0, 0);
            }
            __builtin_amdgcn_s_setprio(0);
        }
        __syncthreads();                      // B: pT + x3 reads done
        if (t < 15) { STAGE_X3(u0 + 64); }    // drains at A(t+1), under S(t+1)
        cur ^= 1;
    }
#undef STAGE_BT
#undef STAGE_X3
#pragma unroll
    for (int g = 0; g < 2; ++g)
#pragma unroll
        for (int js = 0; js < 4; ++js)
#pragma unroll
            for (int r = 0; r < 4; ++r)
                Yp[((size_t)b * NN + iw + g * 16 + quad * 4 + r) * CHH +
                   j0 + js * 16 + m] = f2bf(yacc[g][js][r]);
}

// ---------------------------------------------------------------------------
// Kernel E: out = x + out_w @ (Yp0+Yp1+Yp2+Yp3)^T + out_b via MFMA
// (proven round 10; flag computed inline since round 17).
// ---------------------------------------------------------------------------
template <typename T>
__device__ __forceinline__ void outconv_body(const T* __restrict__ x,
                                             const unsigned short* __restrict__ Yp0,
                                             const unsigned short* __restrict__ Yp1,
                                             const unsigned short* __restrict__ Yp2,
                                             const unsigned short* __restrict__ Yp3,
                                             const unsigned short* __restrict__ OWb,
                                             const float* __restrict__ OBf,
                                             T* __restrict__ out) {
    int b = blockIdx.y;
    int p0 = blockIdx.x * 16;
    int flat = threadIdx.x;
    int w = flat >> 6, lane = flat & 63, m = lane & 15, quad = lane >> 4;
    size_t yoff = ((size_t)b * NN + p0 + m) * CHH;
    const unsigned short* yrows[4] = {Yp0 + yoff, Yp1 + yoff, Yp2 + yoff, Yp3 + yoff};
    bf16x8 yf[4][4];
#pragma unroll
    for (int pz = 0; pz < 4; ++pz)
#pragma unroll
        for (int kc = 0; kc < 4; ++kc)
            yf[pz][kc] = ldb8(&yrows[pz][kc * 32 + quad * 8]);
#pragma unroll
    for (int q = 0; q < 4; ++q) {
        int o0 = (w * 4 + q) * 16;
        const unsigned short* wrow = OWb + (size_t)(o0 + m) * CHH;
        f32x4 acc = {0.f, 0.f, 0.f, 0.f};
        __builtin_amdgcn_s_setprio(1);
#pragma unroll
        for (int kc = 0; kc < 4; ++kc) {
            bf16x8 aw = ldb8(&wrow[kc * 32 + quad * 8]);
#pragma unroll
            for (int pz = 0; pz < 4; ++pz)
                acc = __builtin_amdgcn_mfma_f32_16x16x32_bf16(aw, yf[pz][kc], acc, 0, 0, 0);
        }
        __builtin_amdgcn_s_setprio(0);
#pragma unroll
        for (int r = 0; r < 4; ++r) {
            int co = o0 + quad * 4 + r;
            size_t oi = ((size_t)b * CC + co) * NN + p0 + m;
            st_f(&out[oi], acc[r] + OBf[co] + to_f(x[oi]));
        }
    }
}

__launch_bounds__(256)
__global__ void outconv_mfma_kernel(const void* x, const void* tb2,
                                    const unsigned short* __restrict__ Yp0,
                                    const unsigned short* __restrict__ Yp1,
                                    const unsigned short* __restrict__ Yp2,
                                    const unsigned short* __restrict__ Yp3,
                                    const unsigned short* __restrict__ OWb,
                                    const float* __restrict__ OBf,
                                    void* out) {
    __shared__ int sflag;
    int flag = detect_flag_block(tb2, &sflag);
    if (flag)
        outconv_body<float>((const float*)x, Yp0, Yp1, Yp2, Yp3, OWb, OBf, (float*)out);
    else
        outconv_body<__hip_bfloat16>((const __hip_bfloat16*)x, Yp0, Yp1, Yp2, Yp3, OWb, OBf,
                                     (__hip_bfloat16*)out);
}

extern "C" void kernel_launch(void* const* d_in, const int* in_sizes, int n_in,
                              void* d_out, int out_size, void* d_ws, size_t ws_size,
                              hipStream_t stream) {
    const void* x  = d_in[0];
    const void* tw = d_in[1];
    const void* tb = d_in[2];
    const void* fw = d_in[3];
    const void* fb = d_in[4];
    const void* gw = d_in[5];
    const void* gb = d_in[6];
    const void* ow = d_in[7];
    const void* ob = d_in[8];

    // Workspace (~30 MB): conv3 (reading x directly) writes T1b natural,
    // T2t fused-transposed, T3b natural; transpose T3b -> X3t. Aliases:
    // Yp0/Yp1 <- scratch, Yp2 <- T3b (dead after transpose), Yp3 fresh.
    const size_t TE = (size_t)BB * CHH * NN;        // 2,097,152
    unsigned short* T1b = (unsigned short*)d_ws;
    unsigned short* T2t = T1b + TE;                 // phi transposed [p][o]
    unsigned short* X3t = T2t + TE;                 // g-view transposed [j][u]
    unsigned short* T3b = X3t + TE;                 // g natural (CH,N)
    unsigned short* xt  = T3b + TE;                 // scratch
    unsigned short* Yp0 = xt;                       // alias
    unsigned short* Yp1 = xt + TE;                  // alias
    unsigned short* Yp2 = T3b;                      // alias (dead after transpose)
    unsigned short* Yp3 = xt + 2 * TE;              // fresh
    unsigned short* Wb  = Yp3 + TE;                 // 98304 shorts
    unsigned short* OWb = Wb + 98304;               // 32768 shorts
    float* Bf    = (float*)(OWb + 32768);           // 384
    float* OBf   = Bf + 384;                        // 256
    float* Lpart = OBf + 256;                       // 8 * BB * NN = 131072

    prep_kernel<<<dim3(515), 256, 0, stream>>>(tw, fw, gw, ow, tb, fb, gb, ob,
                                               Wb, OWb, Bf, OBf);
    conv3_mfma_kernel<<<dim3(NN / 16, BB), 256, 0, stream>>>(x, tb, Wb, Bf, T1b, T2t, T3b);
    trans_stats_kernel<<<dim3(1024), 256, 0, stream>>>(T1b, T2t, T3b, X3t, Lpart);
    attn_mfma_kernel<<<dim3(512), 512, 0, stream>>>(T1b, T2t, X3t, Lpart, Yp0, Yp1, Yp2, Yp3);
    outconv_mfma_kernel<<<dim3(NN / 16, BB), 256, 0, stream>>>(x, tb, Yp0, Yp1, Yp2, Yp3,
                                                               OWb, OBf, d_out);
}

// Round 14
// 188.638 us; speedup vs baseline: 1.0604x; 1.0604x over previous
//
#include <hip/hip_runtime.h>
#include <hip/hip_bf16.h>

#define BB 4
#define CC 256
#define CHH 128
#define NN 4096
#define KSHIFT2 17.312340490667562f   // 12 * log2(e); phi pre-scaled by log2(e)
#define LOG2E 1.4426950408889634f

typedef __attribute__((ext_vector_type(8))) short bf16x8;
typedef __attribute__((ext_vector_type(4))) float f32x4;

__device__ __forceinline__ float to_f(float v) { return v; }
__device__ __forceinline__ float to_f(__hip_bfloat16 v) { return __bfloat162float(v); }
__device__ __forceinline__ void st_f(float* p, float v) { *p = v; }
__device__ __forceinline__ void st_f(__hip_bfloat16* p, float v) { *p = __float2bfloat16(v); }
__device__ __forceinline__ unsigned short f2bf(float f) {
    __hip_bfloat16 h = __float2bfloat16(f);
    unsigned short u;
    __builtin_memcpy(&u, &h, 2);
    return u;
}
__device__ __forceinline__ bf16x8 ldb8(const unsigned short* p) { return *(const bf16x8*)p; }

// Raw 2^x: v_exp_f32 IS exp2 in hardware (proven round 23: OCML exp2f cost
// +12pts VALUBusy; this is one instruction).
__device__ __forceinline__ float fexp2(float x) {
    float r;
    asm("v_exp_f32 %0, %1" : "=v"(r) : "v"(x));
    return r;
}

// async global->LDS, 16 B per lane. LDS dest = wave-uniform base + lane*16.
__device__ __forceinline__ void gload_lds16(const unsigned short* g, unsigned short* l) {
    __builtin_amdgcn_global_load_lds(
        (const __attribute__((address_space(1))) unsigned int*)g,
        (__attribute__((address_space(3))) unsigned int*)l, 16, 0, 0);
}

// vectorized 16-element row load (bf16 or f32 wire) -> 16 bf16 u16
__device__ __forceinline__ void load16(const __hip_bfloat16* src, unsigned short* v) {
    bf16x8 a = *(const bf16x8*)src;
    bf16x8 b = *(const bf16x8*)(src + 8);
#pragma unroll
    for (int k = 0; k < 8; ++k) {
        v[k] = ((unsigned short*)&a)[k];
        v[8 + k] = ((unsigned short*)&b)[k];
    }
}
__device__ __forceinline__ void load16(const float* src, unsigned short* v) {
#pragma unroll
    for (int q = 0; q < 4; ++q) {
        f32x4 f = *(const f32x4*)(src + q * 4);
#pragma unroll
        for (int k = 0; k < 4; ++k) v[q * 4 + k] = f2bf(f[k]);
    }
}

// ---------------------------------------------------------------------------
// Inline wire-dtype detection (proven heuristic, rounds 3-10).
// ---------------------------------------------------------------------------
__device__ __forceinline__ int detect_flag_block(const void* tb, int* sflag) {
    int tid = threadIdx.x;
    if (tid < 64) {
        const __hip_bfloat16* p = (const __hip_bfloat16*)tb;
        int big = 0, zero_even = 0;
#pragma unroll
        for (int k = 0; k < 2; ++k) {
            int idx = tid * 2 + k;
            float v = __bfloat162float(p[idx]);
            if (!(fabsf(v) <= 0.5f)) big = 1;
            if ((idx & 1) == 0 && v == 0.0f) zero_even = 1;
        }
        unsigned long long bigm = __ballot(big);
        unsigned long long zm = __ballot(zero_even);
        if (tid == 0) *sflag = (bigm != 0ULL || __popcll(zm) >= 32) ? 1 : 0;
    }
    __syncthreads();
    return *sflag;
}

// ---------------------------------------------------------------------------
// Kernel A: prep only (xtrans deleted round 22). log2(e) folded into phi.
// ---------------------------------------------------------------------------
template <typename T>
__device__ __forceinline__ void prep_body(const T* tw, const T* fw, const T* gw, const T* ow,
                                          const T* tb2, const T* fb, const T* gb, const T* ob,
                                          unsigned short* Wb, unsigned short* OWb,
                                          float* Bf, float* OBf) {
    int idx = blockIdx.x * 256 + threadIdx.x;
    if (idx < 98304) {
        int cv = idx >> 15, rem = idx & 32767;
        const T* src = cv == 0 ? tw : (cv == 1 ? fw : gw);
        float v = to_f(src[rem]);
        if (cv == 1) v *= LOG2E;              // phi scaled: S' = S*log2e
        Wb[idx] = f2bf(v);
    } else if (idx < 131072) {
        OWb[idx - 98304] = f2bf(to_f(ow[idx - 98304]));
    } else if (idx < 131456) {
        int r = idx - 131072;
        int cv = r >> 7, j = r & 127;
        const T* src = cv == 0 ? tb2 : (cv == 1 ? fb : gb);
        float v = to_f(src[j]);
        if (cv == 1) v *= LOG2E;
        Bf[r] = v;
    } else if (idx < 131712) {
        OBf[idx - 131456] = to_f(ob[idx - 131456]);
    }
}

__launch_bounds__(256)
__global__ void prep_kernel(const void* tw, const void* fw, const void* gw, const void* ow,
                            const void* tb2, const void* fb, const void* gb, const void* ob,
                            unsigned short* Wb, unsigned short* OWb, float* Bf, float* OBf) {
    __shared__ int sflag;
    int flag = detect_flag_block(tb2, &sflag);
    if (flag)
        prep_body<float>((const float*)tw, (const float*)fw, (const float*)gw, (const float*)ow,
                         (const float*)tb2, (const float*)fb, (const float*)gb, (const float*)ob,
                         Wb, OWb, Bf, OBf);
    else
        prep_body<__hip_bfloat16>((const __hip_bfloat16*)tw, (const __hip_bfloat16*)fw,
                                  (const __hip_bfloat16*)gw, (const __hip_bfloat16*)ow,
                                  (const __hip_bfloat16*)tb2, (const __hip_bfloat16*)fb,
                                  (const __hip_bfloat16*)gb, (const __hip_bfloat16*)ob,
                                  Wb, OWb, Bf, OBf);
}

// ---------------------------------------------------------------------------
// Kernel B: three 1x1 convs via MFMA, reading x directly with in-kernel
// transpose staging (proven round 22; xt intermediate deleted).
// ---------------------------------------------------------------------------
template <typename T>
__device__ __forceinline__ void conv3_body(const T* __restrict__ x,
                                           const unsigned short* __restrict__ Wb,
                                           const float* __restrict__ Bf,
                                           unsigned short* __restrict__ T1b,
                                           unsigned short* __restrict__ T2t,
                                           unsigned short* __restrict__ T3b,
                                           unsigned short (*t)[272]) {
    int b = blockIdx.y;
    int p0 = blockIdx.x * 16;
    int flat = threadIdx.x;
    int w = flat >> 6, lane = flat & 63, m = lane & 15, quad = lane >> 4;
    {   // stage + transpose: thread c reads 16 consecutive p of row c
        int c = flat;
        const T* src = x + ((size_t)b * CC + c) * NN + p0;
        unsigned short v[16];
        load16(src, v);
#pragma unroll
        for (int pp = 0; pp < 16; ++pp) t[pp][c] = v[pp];   // lanes contiguous in c
    }
    __syncthreads();
    bf16x8 xf[8];
#pragma unroll
    for (int kc = 0; kc < 8; ++kc)
        xf[kc] = ldb8(&t[m][kc * 32 + quad * 8]);
    unsigned short* t1  = T1b + (size_t)b * CHH * NN;
    unsigned short* t2t = T2t + (size_t)b * CHH * NN;   // [p][o], row stride 128
    unsigned short* t3  = T3b + (size_t)b * CHH * NN;   // natural (CH,N)
#pragma unroll
    for (int q = 0; q < 6; ++q) {
        int tt = w * 6 + q;
        int cv = tt >> 3, ot = tt & 7;
        int o0 = ot * 16;
        const unsigned short* wrow = Wb + ((size_t)cv * CHH + o0 + m) * CC;
        f32x4 acc = {0.f, 0.f, 0.f, 0.f};
        __builtin_amdgcn_s_setprio(1);
#pragma unroll
        for (int kc = 0; kc < 8; ++kc) {
            bf16x8 wf = ldb8(&wrow[kc * 32 + quad * 8]);
            acc = __builtin_amdgcn_mfma_f32_16x16x32_bf16(wf, xf[kc], acc, 0, 0, 0);
        }
        __builtin_amdgcn_s_setprio(0);
        unsigned short hv[4];
#pragma unroll
        for (int r = 0; r < 4; ++r)
            hv[r] = f2bf(acc[r] + Bf[cv * CHH + o0 + quad * 4 + r]);
        if (cv == 1) {
            unsigned int lo = (unsigned int)hv[0] | ((unsigned int)hv[1] << 16);
            unsigned int hi = (unsigned int)hv[2] | ((unsigned int)hv[3] << 16);
            int src = (lane & 3) * 16 + (lane >> 2);
            unsigned int tlo = (unsigned int)__shfl((int)lo, src, 64);
            unsigned int thi = (unsigned int)__shfl((int)hi, src, 64);
            unsigned int* dst = (unsigned int*)&t2t[(size_t)(p0 + (lane >> 2)) * CHH +
                                                    o0 + (lane & 3) * 4];
            dst[0] = tlo;
            dst[1] = thi;
        } else {
            unsigned short* outp = (cv == 0) ? t1 : t3;
#pragma unroll
            for (int r = 0; r < 4; ++r)
                outp[(size_t)(o0 + quad * 4 + r) * NN + p0 + m] = hv[r];
        }
    }
}

__launch_bounds__(256)
__global__ void conv3_mfma_kernel(const void* x, const void* tb2,
                                  const unsigned short* __restrict__ Wb,
                                  const float* __restrict__ Bf,
                                  unsigned short* __restrict__ T1b,
                                  unsigned short* __restrict__ T2t,
                                  unsigned short* __restrict__ T3b) {
    __shared__ int sflag;
    __shared__ unsigned short t[16][272];     // 8,704 B transpose tile
    int flag = detect_flag_block(tb2, &sflag);
    if (flag)
        conv3_body<float>((const float*)x, Wb, Bf, T1b, T2t, T3b, t);
    else
        conv3_body<__hip_bfloat16>((const __hip_bfloat16*)x, Wb, Bf, T1b, T2t, T3b, t);
}

// ---------------------------------------------------------------------------
// Kernel C: transpose + stats fused — EXACT round-12 form (proven 190.2 us
// total). ROUND 25 note: round-13's high-intensity variant (64-u waves,
// bfr[4][4], 512 stats blocks) REGRESSED ~10 us — halved block-level
// parallelism + VGPR pressure cost more than the halved LDS traffic saved.
// Blocks 0..1023: stats (long pole, dispatched first); 1024..1535: X3t
// transpose.
// ---------------------------------------------------------------------------
__launch_bounds__(256)
__global__ void trans_stats_kernel(const unsigned short* __restrict__ T1b,
                                   const unsigned short* __restrict__ T2t,
                                   const unsigned short* __restrict__ T3b,
                                   unsigned short* __restrict__ X3t,
                                   float* __restrict__ Lpart) {
    __shared__ unsigned short arena[2 * 64 * 128];   // 32 KB
    int flat = threadIdx.x;
    if (blockIdx.x >= 1024) {
        // ---- transpose part: X3t (NN x CHH view) <- T3b, 64x64 tiles ----
        int id = blockIdx.x - 1024;            // 0..511
        int bz = id >> 7;                      // batch
        int by = (id >> 1) & 63;               // row tile (NN)
        int bx = id & 1;                       // col tile (CHH)
        const unsigned short* in = T3b + (size_t)bz * NN * CHH;
        unsigned short* out = X3t + (size_t)bz * NN * CHH;
        int c0 = bx * 64, r0 = by * 64;
        unsigned short (*t)[68] = (unsigned short (*)[68])arena;
#pragma unroll
        for (int tt = 0; tt < 16; ++tt) {
            int id2 = flat + tt * 256;
            int r = id2 >> 6, c = id2 & 63;
            t[c][r] = in[(size_t)(r0 + r) * CHH + c0 + c];
        }
        __syncthreads();
#pragma unroll
        for (int tt = 0; tt < 16; ++tt) {
            int id2 = flat + tt * 256;
            int c = id2 >> 6, r = id2 & 63;
            out[(size_t)(c0 + c) * NN + r0 + r] = t[c][r];
        }
        return;
    }
    // ---- stats part: colsum exp2(S'-K2), dbuf + single barrier ----
    int blk = blockIdx.x;
    int b = (blk & 7) >> 1;
    int rest = (blk >> 3) * 2 + (blk & 1);   // 0..255 = strip*8 + iq
    int strip = rest >> 3, iq = rest & 7;
    int ibase = iq * 512;
    int w = flat >> 6, lane = flat & 63, m = lane & 15, quad = lane >> 4;
    const unsigned short* A  = T1b + (size_t)b * CHH * NN;
    const unsigned short* Bt = T2t + (size_t)b * CHH * NN;

    int u0w = strip * 128 + w * 32;           // this wave's 32-u window
    bf16x8 bfr[2][4];
#pragma unroll
    for (int g = 0; g < 2; ++g)
#pragma unroll
        for (int kc = 0; kc < 4; ++kc)
            bfr[g][kc] = ldb8(&Bt[(size_t)(u0w + g * 16 + m) * CHH + kc * 32 + quad * 8]);

#define STAGE_TH(dst, ii)                                                          \
    _Pragma("unroll")                                                              \
    for (int i_ = 0; i_ < 4; ++i_) {                                               \
        int sl = i_ * 256 + flat;                                                  \
        int r_ = sl >> 4, ch_ = sl & 15;                                           \
        int c_ = ch_ ^ (r_ & 7);                                                   \
        gload_lds16(&A[(size_t)((ii) + r_) * CHH + c_ * 8],                        \
                    arena + (dst) * 8192 + sl * 8);                                \
    }

    float csum[2] = {0.f, 0.f};
    STAGE_TH(0, ibase);                      // prologue: tile 0
    __syncthreads();                         // tile 0 ready (vmcnt drained)
    int cur = 0;
    for (int t = 0; t < 8; ++t) {            // 8 i-tiles of 64 in this chunk
        if (t < 7) { STAGE_TH(cur ^ 1, ibase + (t + 1) * 64); }
        const unsigned short* thc = arena + cur * 8192;
#pragma unroll
        for (int s = 0; s < 4; ++s) {
            int irow = s * 16 + m;
            bf16x8 af[4];
#pragma unroll
            for (int kc = 0; kc < 4; ++kc) {
                int ch = (kc * 4 + quad) ^ (irow & 7);
                af[kc] = *(const bf16x8*)&thc[irow * 128 + ch * 8];
            }
            __builtin_amdgcn_s_setprio(1);
#pragma unroll
            for (int g = 0; g < 2; ++g) {
                f32x4 acc = {0.f, 0.f, 0.f, 0.f};
#pragma unroll
                for (int kc = 0; kc < 4; ++kc)
                    acc = __builtin_amdgcn_mfma_f32_16x16x32_bf16(af[kc], bfr[g][kc], acc, 0, 0, 0);
#pragma unroll
                for (int r = 0; r < 4; ++r)
                    csum[g] += fexp2(acc[r] - KSHIFT2);
            }
            __builtin_amdgcn_s_setprio(0);
        }
        if (t < 7) {
            __syncthreads();                 // publishes tile t+1, protects buf t
            cur ^= 1;
        }
    }
#undef STAGE_TH
#pragma unroll
    for (int g = 0; g < 2; ++g) {
        csum[g] += __shfl_xor(csum[g], 16, 64);
        csum[g] += __shfl_xor(csum[g], 32, 64);
        if (lane < 16)
            Lpart[((size_t)iq * BB + b) * NN + u0w + g * 16 + m] = csum[g];
    }
}

// ---------------------------------------------------------------------------
// Kernel D (pass B): Y = P @ X3. Round-23 swapped-S structure (proven
// ~47 us): raw v_exp_f32 + __log2f; phi pre-scaled by log2e. Unchanged.
// ---------------------------------------------------------------------------
__launch_bounds__(512, 2)
__global__ void attn_mfma_kernel(const unsigned short* __restrict__ T1b,
                                 const unsigned short* __restrict__ T2t,
                                 const unsigned short* __restrict__ X3t,
                                 const float* __restrict__ Lpart,
                                 unsigned short* __restrict__ Yp0,
                                 unsigned short* __restrict__ Yp1,
                                 unsigned short* __restrict__ Yp2,
                                 unsigned short* __restrict__ Yp3) {
    int blk = blockIdx.x;
    int b = (blk & 7) >> 1;
    int rest = (blk >> 3) * 2 + (blk & 1);   // 0..127 = it*4 + uc
    int it = rest >> 2, uc = rest & 3;
    int i0 = it * 128;
    unsigned short* Yp = uc == 0 ? Yp0 : (uc == 1 ? Yp1 : (uc == 2 ? Yp2 : Yp3));
    int flat = threadIdx.x;                   // 0..511
    int w = flat >> 6, lane = flat & 63, m = lane & 15, quad = lane >> 4;
    int ig = w & 3, h = w >> 2;               // i-group (32 rows), j-half/u-half
    const unsigned short* A  = T1b + (size_t)b * CHH * NN;
    const unsigned short* Bt = T2t + (size_t)b * CHH * NN;
    const unsigned short* X3 = X3t + (size_t)b * CHH * NN;

    // LDS arena, 69,632 B:
    //   [     0, 32768) bt   : phi^T tile, swizzled, dbuf 2 x 64x128 bf16
    //   [ 32768, 49152) x3   : X3 tile, swizzled, single 128x64 bf16
    //   [ 49152, 65536) pT   : per-ig P tiles [4][32 rows][64] bf16, XOR-swz
    //   [ 65536, 69632) llh  : 1024 f32 LL values
    __shared__ __align__(16) unsigned char smem[69632];
    unsigned short* bt0 = (unsigned short*)smem;
    unsigned short* x3s = (unsigned short*)(smem + 32768);
    unsigned short* pTg = (unsigned short*)(smem + 49152) + ig * 2048; // [32][64]
    float* llh = (float*)(smem + 65536);

    int ubeg = uc * 1024;
#pragma unroll
    for (int k = 0; k < 2; ++k) {             // LL prologue
        int idx = k * 512 + flat;
        int u = ubeg + idx;
        float s = 0.f;
#pragma unroll
        for (int c = 0; c < 8; ++c)
            s += Lpart[((size_t)c * BB + b) * NN + u];
        llh[idx] = __log2f(s) + KSHIFT2;
    }

    int iw = i0 + ig * 32;                    // this wave's 32 i-rows
    int j0 = h * 64;                          // this wave's 64 j-cols
    bf16x8 ath[2][4];
#pragma unroll
    for (int g = 0; g < 2; ++g)
#pragma unroll
        for (int kc = 0; kc < 4; ++kc)
            ath[g][kc] = ldb8(&A[(size_t)(iw + g * 16 + m) * CHH + kc * 32 + quad * 8]);
    f32x4 yacc[2][4];
#pragma unroll
    for (int g = 0; g < 2; ++g)
#pragma unroll
        for (int js = 0; js < 4; ++js) yacc[g][js] = (f32x4){0.f, 0.f, 0.f, 0.f};

#define STAGE_BT(dst, uu)                                                          \
    _Pragma("unroll")                                                              \
    for (int i_ = 0; i_ < 2; ++i_) {          /* 16 KB */                          \
        int sl = i_ * 512 + flat;                                                  \
        int u_ = sl >> 4, ch_ = sl & 15;                                           \
        int c_ = ch_ ^ (u_ & 7);                                                   \
        gload_lds16(&Bt[(size_t)((uu) + u_) * CHH + c_ * 8],                       \
                    bt0 + (dst) * 8192 + sl * 8);                                  \
    }
#define STAGE_X3(uu)                                                               \
    _Pragma("unroll")                                                              \
    for (int i_ = 0; i_ < 2; ++i_) {          /* 16 KB */                          \
        int sl = i_ * 512 + flat;                                                  \
        int j_ = sl >> 3, ch_ = sl & 7;                                            \
        int c_ = ch_ ^ (j_ & 7);                                                   \
        gload_lds16(&X3[(size_t)j_ * NN + (uu) + c_ * 8], x3s + sl * 8);           \
    }

    STAGE_BT(0, ubeg);                        // prologue: bt tile 0 + x3 tile 0
    STAGE_X3(ubeg);
    __syncthreads();                          // staging drained + llh visible
    int cur = 0;
    for (int t = 0; t < 16; ++t) {
        int u0 = ubeg + t * 64;
        if (t < 15) { STAGE_BT(cur ^ 1, u0 + 64); }   // drains at barrier A
        const unsigned short* btc = bt0 + cur * 8192;
        // ---- S phase (swapped): S^T(32u-half h x 32i), exp, packed P ----
#pragma unroll
        for (int su = 0; su < 2; ++su) {
            int ul = h * 32 + su * 16 + m;    // bt row fed as A-operand rows
            f32x4 a0 = {0.f, 0.f, 0.f, 0.f}, a1 = {0.f, 0.f, 0.f, 0.f};
            __builtin_amdgcn_s_setprio(1);
#pragma unroll
            for (int kc = 0; kc < 4; ++kc) {
                int ch = (kc * 4 + quad) ^ (ul & 7);
                bf16x8 bf = *(const bf16x8*)&btc[ul * 128 + ch * 8];
                a0 = __builtin_amdgcn_mfma_f32_16x16x32_bf16(bf, ath[0][kc], a0, 0, 0, 0);
                a1 = __builtin_amdgcn_mfma_f32_16x16x32_bf16(bf, ath[1][kc], a1, 0, 0, 0);
            }
            __builtin_amdgcn_s_setprio(0);
            // lane holds P^T: i = m (+g*16), u = ubase + r (4 consecutive u)
            int ubase = h * 32 + su * 16 + quad * 4;
            int lb = t * 64 + ubase;
            unsigned int p00 = (unsigned int)f2bf(fexp2(a0[0] - llh[lb + 0])) |
                               ((unsigned int)f2bf(fexp2(a0[1] - llh[lb + 1])) << 16);
            unsigned int p01 = (unsigned int)f2bf(fexp2(a0[2] - llh[lb + 2])) |
                               ((unsigned int)f2bf(fexp2(a0[3] - llh[lb + 3])) << 16);
            unsigned int p10 = (unsigned int)f2bf(fexp2(a1[0] - llh[lb + 0])) |
                               ((unsigned int)f2bf(fexp2(a1[1] - llh[lb + 1])) << 16);
            unsigned int p11 = (unsigned int)f2bf(fexp2(a1[2] - llh[lb + 2])) |
                               ((unsigned int)f2bf(fexp2(a1[3] - llh[lb + 3])) << 16);
            int chs = ((ubase >> 3) ^ (m & 7)) * 8 + (ubase & 7); // swz chunk+off
            unsigned int* d0 = (unsigned int*)&pTg[m * 64 + chs];          // 4B-aligned
            d0[0] = p00; d0[1] = p01;
            unsigned int* d1 = (unsigned int*)&pTg[(16 + m) * 64 + chs];
            d1[0] = p10; d1[1] = p11;
        }
        __syncthreads();                      // A: pT published; x3(t)+bt(t+1) drained
        // ---- PV phase: Y(32i x 64j, cols j0..j0+63) over full 64-u K ----
#pragma unroll
        for (int ku = 0; ku < 2; ++ku) {
            bf16x8 pa0 = *(const bf16x8*)&pTg[m * 64 + ((ku * 4 + quad) ^ (m & 7)) * 8];
            bf16x8 pa1 = *(const bf16x8*)&pTg[(16 + m) * 64 + ((ku * 4 + quad) ^ (m & 7)) * 8];
            __builtin_amdgcn_s_setprio(1);
#pragma unroll
            for (int js = 0; js < 4; ++js) {
                int j = j0 + js * 16 + m;
                int ch = (ku * 4 + quad) ^ (j & 7);
                bf16x8 xb = *(const bf16x8*)&x3s[j * 64 + ch * 8];
                yacc[0][js] = __builtin_amdgcn_mfma_f32_16x16x32_bf16(pa0, xb, yacc[0][js], 0, 0, 0);
                yacc[1][js] = __builtin_amdgcn_mfma_f32_16x16x32_bf16(pa1, xb, yacc[1][js], 0, 0, 0);
            }
            __builtin_amdgcn_s_setprio(0);
        }
        __syncthreads();                      // B: pT + x3 reads done
        if (t < 15) { STAGE_X3(u0 + 64); }    // drains at A(t+1), under S(t+1)
        cur ^= 1;
    }
#undef STAGE_BT
#undef STAGE_X3
#pragma unroll
    for (int g = 0; g < 2; ++g)
#pragma unroll
        for (int js = 0; js < 4; ++js)
#pragma unroll
            for (int r = 0; r < 4; ++r)
                Yp[((size_t)b * NN + iw + g * 16 + quad * 4 + r) * CHH +
                   j0 + js * 16 + m] = f2bf(yacc[g][js][r]);
}

// ---------------------------------------------------------------------------
// Kernel E: out = x + out_w @ (Yp0+Yp1+Yp2+Yp3)^T + out_b via MFMA
// (proven round 10; flag computed inline since round 17).
// ---------------------------------------------------------------------------
template <typename T>
__device__ __forceinline__ void outconv_body(const T* __restrict__ x,
                                             const unsigned short* __restrict__ Yp0,
                                             const unsigned short* __restrict__ Yp1,
                                             const unsigned short* __restrict__ Yp2,
                                             const unsigned short* __restrict__ Yp3,
                                             const unsigned short* __restrict__ OWb,
                                             const float* __restrict__ OBf,
                                             T* __restrict__ out) {
    int b = blockIdx.y;
    int p0 = blockIdx.x * 16;
    int flat = threadIdx.x;
    int w = flat >> 6, lane = flat & 63, m = lane & 15, quad = lane >> 4;
    size_t yoff = ((size_t)b * NN + p0 + m) * CHH;
    const unsigned short* yrows[4] = {Yp0 + yoff, Yp1 + yoff, Yp2 + yoff, Yp3 + yoff};
    bf16x8 yf[4][4];
#pragma unroll
    for (int pz = 0; pz < 4; ++pz)
#pragma unroll
        for (int kc = 0; kc < 4; ++kc)
            yf[pz][kc] = ldb8(&yrows[pz][kc * 32 + quad * 8]);
#pragma unroll
    for (int q = 0; q < 4; ++q) {
        int o0 = (w * 4 + q) * 16;
        const unsigned short* wrow = OWb + (size_t)(o0 + m) * CHH;
        f32x4 acc = {0.f, 0.f, 0.f, 0.f};
        __builtin_amdgcn_s_setprio(1);
#pragma unroll
        for (int kc = 0; kc < 4; ++kc) {
            bf16x8 aw = ldb8(&wrow[kc * 32 + quad * 8]);
#pragma unroll
            for (int pz = 0; pz < 4; ++pz)
                acc = __builtin_amdgcn_mfma_f32_16x16x32_bf16(aw, yf[pz][kc], acc, 0, 0, 0);
        }
        __builtin_amdgcn_s_setprio(0);
#pragma unroll
        for (int r = 0; r < 4; ++r) {
            int co = o0 + quad * 4 + r;
            size_t oi = ((size_t)b * CC + co) * NN + p0 + m;
            st_f(&out[oi], acc[r] + OBf[co] + to_f(x[oi]));
        }
    }
}

__launch_bounds__(256)
__global__ void outconv_mfma_kernel(const void* x, const void* tb2,
                                    const unsigned short* __restrict__ Yp0,
                                    const unsigned short* __restrict__ Yp1,
                                    const unsigned short* __restrict__ Yp2,
                                    const unsigned short* __restrict__ Yp3,
                                    const unsigned short* __restrict__ OWb,
                                    const float* __restrict__ OBf,
                                    void* out) {
    __shared__ int sflag;
    int flag = detect_flag_block(tb2, &sflag);
    if (flag)
        outconv_body<float>((const float*)x, Yp0, Yp1, Yp2, Yp3, OWb, OBf, (float*)out);
    else
        outconv_body<__hip_bfloat16>((const __hip_bfloat16*)x, Yp0, Yp1, Yp2, Yp3, OWb, OBf,
                                     (__hip_bfloat16*)out);
}

extern "C" void kernel_launch(void* const* d_in, const int* in_sizes, int n_in,
                              void* d_out, int out_size, void* d_ws, size_t ws_size,
                              hipStream_t stream) {
    const void* x  = d_in[0];
    const void* tw = d_in[1];
    const void* tb = d_in[2];
    const void* fw = d_in[3];
    const void* fb = d_in[4];
    const void* gw = d_in[5];
    const void* gb = d_in[6];
    const void* ow = d_in[7];
    const void* ob = d_in[8];

    // Workspace (~30 MB): conv3 (reading x directly) writes T1b natural,
    // T2t fused-transposed, T3b natural; transpose T3b -> X3t. Aliases:
    // Yp0/Yp1 <- scratch, Yp2 <- T3b (dead after transpose), Yp3 fresh.
    const size_t TE = (size_t)BB * CHH * NN;        // 2,097,152
    unsigned short* T1b = (unsigned short*)d_ws;
    unsigned short* T2t = T1b + TE;                 // phi transposed [p][o]
    unsigned short* X3t = T2t + TE;                 // g-view transposed [j][u]
    unsigned short* T3b = X3t + TE;                 // g natural (CH,N)
    unsigned short* xt  = T3b + TE;                 // scratch
    unsigned short* Yp0 = xt;                       // alias
    unsigned short* Yp1 = xt + TE;                  // alias
    unsigned short* Yp2 = T3b;                      // alias (dead after transpose)
    unsigned short* Yp3 = xt + 2 * TE;              // fresh
    unsigned short* Wb  = Yp3 + TE;                 // 98304 shorts
    unsigned short* OWb = Wb + 98304;               // 32768 shorts
    float* Bf    = (float*)(OWb + 32768);           // 384
    float* OBf   = Bf + 384;                        // 256
    float* Lpart = OBf + 256;                       // 8 * BB * NN = 131072

    prep_kernel<<<dim3(515), 256, 0, stream>>>(tw, fw, gw, ow, tb, fb, gb, ob,
                                               Wb, OWb, Bf, OBf);
    conv3_mfma_kernel<<<dim3(NN / 16, BB), 256, 0, stream>>>(x, tb, Wb, Bf, T1b, T2t, T3b);
    trans_stats_kernel<<<dim3(1536), 256, 0, stream>>>(T1b, T2t, T3b, X3t, Lpart);
    attn_mfma_kernel<<<dim3(512), 512, 0, stream>>>(T1b, T2t, X3t, Lpart, Yp0, Yp1, Yp2, Yp3);
    outconv_mfma_kernel<<<dim3(NN / 16, BB), 256, 0, stream>>>(x, tb, Yp0, Yp1, Yp2, Yp3,
                                                               OWb, OBf, d_out);
}